// Round 1
// baseline (277.768 us; speedup 1.0000x reference)
//
#include <hip/hip_runtime.h>

#define KK 3
#define W_OUT 12
#define N_CAPS 288   // Ci*K*K
#define CIN 8
#define DD 16
#define A_DIM 32
#define B_DIM 4
#define CI 32
#define H_IN 14
#define ITERS 3
#define PS_STRIDE 17

__global__ __launch_bounds__(256) void capsule_kernel(
    const float* __restrict__ x,
    const float* __restrict__ Wt,
    const float* __restrict__ bias,
    float* __restrict__ out)
{
    __shared__ float xs[N_CAPS * CIN];        // 9216 B
    __shared__ float ps[N_CAPS * PS_STRIDE];  // 19584 B, stride-17 pad kills bank conflicts
    __shared__ float logits[N_CAPS];
    __shared__ float probs[N_CAPS];
    __shared__ float red[256];
    __shared__ float sArr[DD];
    __shared__ float outArr[DD];

    const int tid = threadIdx.x;
    int bid = blockIdx.x;
    const int j = bid % W_OUT; bid /= W_OUT;
    const int i = bid % W_OUT; bid /= W_OUT;
    const int b = bid % B_DIM; bid /= B_DIM;
    const int a = bid;

    // ---- load x window into LDS: xs[n*8+c] = x[b, ci, i+ki, j+kj, c], n=ci*9+ki*3+kj
    for (int idx = tid; idx < N_CAPS * 2; idx += 256) {
        int n    = idx >> 1;
        int half = idx & 1;
        int ci = n / 9;
        int r  = n % 9;
        int ki = r / 3, kj = r % 3;
        const float* src = x + ((((size_t)b * CI + ci) * H_IN + (i + ki)) * H_IN + (j + kj)) * CIN + half * 4;
        float4 v = *reinterpret_cast<const float4*>(src);
        *reinterpret_cast<float4*>(&xs[n * CIN + half * 4]) = v;
    }
    __syncthreads();

    // ---- priors: ps[n][d] = sum_c xs[n][c] * W[a][n][c][d]
    const float* Wa = Wt + (size_t)a * N_CAPS * CIN * DD;
    for (int p = tid; p < N_CAPS * DD; p += 256) {
        int n = p >> 4;
        int d = p & 15;
        const float* wrow = Wa + n * (CIN * DD) + d;
        const float* xr   = &xs[n * CIN];
        float acc = 0.f;
        #pragma unroll
        for (int c = 0; c < CIN; ++c)
            acc = fmaf(xr[c], wrow[c * DD], acc);
        ps[n * PS_STRIDE + d] = acc;
    }

    // ---- init logits
    for (int n = tid; n < N_CAPS; n += 256) logits[n] = 0.f;
    __syncthreads();

    const float bd = (tid < DD) ? bias[a * DD + tid] : 0.f;
    float factor = 0.f;

    for (int it = 0; it < ITERS; ++it) {
        // softmax over n (288)
        float m = -1e30f;
        for (int n = tid; n < N_CAPS; n += 256) m = fmaxf(m, logits[n]);
        red[tid] = m; __syncthreads();
        for (int s = 128; s > 0; s >>= 1) {
            if (tid < s) red[tid] = fmaxf(red[tid], red[tid + s]);
            __syncthreads();
        }
        float M = red[0];
        __syncthreads();
        float lsum = 0.f;
        for (int n = tid; n < N_CAPS; n += 256) {
            float e = __expf(logits[n] - M);
            probs[n] = e;
            lsum += e;
        }
        red[tid] = lsum; __syncthreads();
        for (int s = 128; s > 0; s >>= 1) {
            if (tid < s) red[tid] += red[tid + s];
            __syncthreads();
        }
        float invS = 1.0f / red[0];
        __syncthreads();

        // s[d] = invS * sum_n probs[n]*ps[n][d] + bias[a][d]
        {
            int d = tid & 15;
            int chunk = tid >> 4;          // 16 chunks x 18 n each
            int n0 = chunk * 18;
            float acc = 0.f;
            #pragma unroll
            for (int k = 0; k < 18; ++k) {
                int n = n0 + k;
                acc = fmaf(probs[n], ps[n * PS_STRIDE + d], acc);
            }
            red[tid] = acc;
        }
        __syncthreads();
        if (tid < DD) {
            float sv = 0.f;
            #pragma unroll
            for (int c = 0; c < 16; ++c) sv += red[c * 16 + tid];
            sv = fmaf(sv, invS, bd);
            sArr[tid] = sv;
        }
        __syncthreads();

        // squash (all threads redundantly; need outArr broadcast anyway)
        float sn = 0.f;
        #pragma unroll
        for (int d = 0; d < DD; ++d) { float v = sArr[d]; sn += v * v; }
        factor = sn / (1.0f + sn) * rsqrtf(sn);
        if (tid < DD) outArr[tid] = factor * sArr[tid];
        __syncthreads();

        if (it != ITERS - 1) {
            // logits[n] += sum_d ps[n][d] * outArr[d]
            for (int n = tid; n < N_CAPS; n += 256) {
                float acc = 0.f;
                #pragma unroll
                for (int d = 0; d < DD; ++d)
                    acc = fmaf(ps[n * PS_STRIDE + d], outArr[d], acc);
                logits[n] += acc;
            }
            __syncthreads();
        } else {
            // out[(((b*A + a)*w + i)*w + j)*D + d]
            if (tid < DD) {
                size_t o = ((((size_t)b * A_DIM + a) * W_OUT + i) * W_OUT + j) * DD + tid;
                out[o] = factor * sArr[tid];
            }
        }
    }
}

extern "C" void kernel_launch(void* const* d_in, const int* in_sizes, int n_in,
                              void* d_out, int out_size, void* d_ws, size_t ws_size,
                              hipStream_t stream) {
    const float* x    = (const float*)d_in[0];
    const float* Wt   = (const float*)d_in[1];
    const float* bias = (const float*)d_in[2];
    float* out = (float*)d_out;
    (void)in_sizes; (void)n_in; (void)out_size; (void)d_ws; (void)ws_size;

    const int grid = A_DIM * B_DIM * W_OUT * W_OUT;  // 18432 sites
    capsule_kernel<<<grid, 256, 0, stream>>>(x, Wt, bias, out);
}

// Round 6
// 161.957 us; speedup vs baseline: 1.7151x; 1.7151x over previous
//
#include <hip/hip_runtime.h>

#define W_OUT 12
#define N_CAPS 288
#define CIN 8
#define DD 16
#define A_DIM 32
#define B_DIM 4
#define CI 32
#define H_IN 14
#define NT 18            // n-rows per lane (288 / 16)
#define XSTRIDE 9        // padded x row stride (floats) — odd => bank spread
#define NROWS 576        // 32 ci * 3 ki * 6 jj

__device__ __forceinline__ float4 shfl_xor4(float4 v, int m) {
    float4 r;
    r.x = __shfl_xor(v.x, m);
    r.y = __shfl_xor(v.y, m);
    r.z = __shfl_xor(v.z, m);
    r.w = __shfl_xor(v.w, m);
    return r;
}

__global__ __launch_bounds__(256, 4) void capsule_kernel(
    const float* __restrict__ x,
    const float* __restrict__ Wt,
    const float* __restrict__ bias,
    float* __restrict__ out)
{
    __shared__ float xs[NROWS * XSTRIDE];   // 20736 B
    __shared__ int   xoff[N_CAPS];          // 1152 B

    const int tid = threadIdx.x;
    int bid = blockIdx.x;
    const int jb = bid % 3; bid /= 3;
    const int i  = bid % W_OUT; bid /= W_OUT;
    const int b  = bid % B_DIM; bid /= B_DIM;
    const int a  = bid;
    const int j0 = jb * 4;

    // xoff[n] = LDS word offset of row n's x data (for sj=0): (ci*18+ki*6+kj)*9
    for (int n = tid; n < N_CAPS; n += 256) {
        int ci = n / 9, r = n % 9;
        xoff[n] = (ci * 18 + (r / 3) * 6 + (r % 3)) * XSTRIDE;
    }

    // stage x window: rows (ci, ki, jj) for jj = 0..5 covering sites j0..j0+3
    for (int row = tid; row < NROWS; row += 256) {
        int ci = row / 18, rr = row % 18;
        int ki = rr / 6, jj = rr % 6;
        const float* src = x + ((((size_t)b * CI + ci) * H_IN + (i + ki)) * H_IN + (j0 + jj)) * CIN;
        float4 v0 = *reinterpret_cast<const float4*>(src);
        float4 v1 = *reinterpret_cast<const float4*>(src + 4);
        float* dst = &xs[row * XSTRIDE];
        dst[0] = v0.x; dst[1] = v0.y; dst[2] = v0.z; dst[3] = v0.w;
        dst[4] = v1.x; dst[5] = v1.y; dst[6] = v1.z; dst[7] = v1.w;
    }
    __syncthreads();
    // ---- no barriers below this point: each wave owns one site ----

    const int lane = tid & 63;
    const int sj   = tid >> 6;          // which of the 4 j-sites (one wave each)
    const int dq   = lane & 3;          // d-quad: lane owns d = 4*dq .. 4*dq+3
    const int nr   = lane >> 2;         // n residue: lane owns n = nr + 16*t

    const float* Wa = Wt + (size_t)a * (N_CAPS * CIN * DD);
    const int sjoff = sj * XSTRIDE;

    // ---- priors in registers: ps[t] = prior[n = nr+16t][4dq..4dq+3]
    float4 ps[NT];
    #pragma unroll
    for (int t = 0; t < NT; ++t) {
        const int n = nr + 16 * t;
        const float* wp = Wa + (size_t)n * (CIN * DD) + dq * 4;
        const float* xp = &xs[xoff[n] + sjoff];
        float4 acc = {0.f, 0.f, 0.f, 0.f};
        #pragma unroll
        for (int c = 0; c < CIN; ++c) {
            float4 w4 = *reinterpret_cast<const float4*>(wp + c * DD);
            float xv = xp[c];
            acc.x = fmaf(xv, w4.x, acc.x);
            acc.y = fmaf(xv, w4.y, acc.y);
            acc.z = fmaf(xv, w4.z, acc.z);
            acc.w = fmaf(xv, w4.w, acc.w);
        }
        ps[t] = acc;
    }

    const float4 bv = *reinterpret_cast<const float4*>(bias + a * DD + dq * 4);

    float lt[NT];     // logits for rows n = nr+16t (replicated across dq lanes)
    float4 out4;

    // ---------- iter 0: logits all zero -> probs = 1/288 ----------
    {
        float4 s = {0.f, 0.f, 0.f, 0.f};
        #pragma unroll
        for (int t = 0; t < NT; ++t) {
            s.x += ps[t].x; s.y += ps[t].y; s.z += ps[t].z; s.w += ps[t].w;
        }
        #pragma unroll
        for (int m = 4; m <= 32; m <<= 1) { float4 o = shfl_xor4(s, m); s.x += o.x; s.y += o.y; s.z += o.z; s.w += o.w; }
        const float inv0 = 1.0f / 288.0f;
        s.x = fmaf(s.x, inv0, bv.x); s.y = fmaf(s.y, inv0, bv.y);
        s.z = fmaf(s.z, inv0, bv.z); s.w = fmaf(s.w, inv0, bv.w);
        float sn = s.x*s.x + s.y*s.y + s.z*s.z + s.w*s.w;
        sn += __shfl_xor(sn, 1); sn += __shfl_xor(sn, 2);
        float factor = sn / (1.0f + sn) * rsqrtf(sn);
        out4.x = factor * s.x; out4.y = factor * s.y; out4.z = factor * s.z; out4.w = factor * s.w;

        #pragma unroll
        for (int t = 0; t < NT; ++t) {
            float p = ps[t].x*out4.x + ps[t].y*out4.y + ps[t].z*out4.z + ps[t].w*out4.w;
            p += __shfl_xor(p, 1);
            p += __shfl_xor(p, 2);
            lt[t] = p;
        }
    }

    // ---------- iters 1, 2 ----------
    #pragma unroll
    for (int it = 1; it < 3; ++it) {
        // softmax over n (288). lt is REPLICATED across the 4 dq lanes, so the
        // denominator reduce must cross nr bits ONLY (masks 4..32) — masks 1,2
        // would count each residue 4x.  (R5 bug: full-wave reduce => se 4x too big.)
        float m = -1e30f;
        #pragma unroll
        for (int t = 0; t < NT; ++t) m = fmaxf(m, lt[t]);
        #pragma unroll
        for (int msk = 4; msk <= 32; msk <<= 1) m = fmaxf(m, __shfl_xor(m, msk));
        float se = 0.f;
        #pragma unroll
        for (int t = 0; t < NT; ++t) se += __expf(lt[t] - m);
        #pragma unroll
        for (int msk = 4; msk <= 32; msk <<= 1) se += __shfl_xor(se, msk);
        const float inv = 1.0f / se;

        float4 s = {0.f, 0.f, 0.f, 0.f};
        #pragma unroll
        for (int t = 0; t < NT; ++t) {
            float e = __expf(lt[t] - m);
            s.x = fmaf(e, ps[t].x, s.x); s.y = fmaf(e, ps[t].y, s.y);
            s.z = fmaf(e, ps[t].z, s.z); s.w = fmaf(e, ps[t].w, s.w);
        }
        #pragma unroll
        for (int msk = 4; msk <= 32; msk <<= 1) { float4 o = shfl_xor4(s, msk); s.x += o.x; s.y += o.y; s.z += o.z; s.w += o.w; }
        s.x = fmaf(s.x, inv, bv.x); s.y = fmaf(s.y, inv, bv.y);
        s.z = fmaf(s.z, inv, bv.z); s.w = fmaf(s.w, inv, bv.w);

        float sn = s.x*s.x + s.y*s.y + s.z*s.z + s.w*s.w;
        sn += __shfl_xor(sn, 1); sn += __shfl_xor(sn, 2);
        float factor = sn / (1.0f + sn) * rsqrtf(sn);
        out4.x = factor * s.x; out4.y = factor * s.y; out4.z = factor * s.z; out4.w = factor * s.w;

        if (it != 2) {
            #pragma unroll
            for (int t = 0; t < NT; ++t) {
                float p = ps[t].x*out4.x + ps[t].y*out4.y + ps[t].z*out4.z + ps[t].w*out4.w;
                p += __shfl_xor(p, 1);
                p += __shfl_xor(p, 2);
                lt[t] += p;
            }
        }
    }

    // ---- store: out[b][a][i][j0+sj][d], 4 lanes (nr==0) x float4 each
    if (nr == 0) {
        size_t o = ((((size_t)b * A_DIM + a) * W_OUT + i) * W_OUT + (j0 + sj)) * DD + dq * 4;
        *reinterpret_cast<float4*>(out + o) = out4;
    }
}

extern "C" void kernel_launch(void* const* d_in, const int* in_sizes, int n_in,
                              void* d_out, int out_size, void* d_ws, size_t ws_size,
                              hipStream_t stream) {
    const float* x    = (const float*)d_in[0];
    const float* Wt   = (const float*)d_in[1];
    const float* bias = (const float*)d_in[2];
    float* out = (float*)d_out;
    (void)in_sizes; (void)n_in; (void)out_size; (void)d_ws; (void)ws_size;

    const int grid = A_DIM * B_DIM * W_OUT * 3;   // 4608 blocks, 4 sites each
    capsule_kernel<<<grid, 256, 0, stream>>>(x, Wt, bias, out);
}

// Round 7
// 142.178 us; speedup vs baseline: 1.9537x; 1.1391x over previous
//
#include <hip/hip_runtime.h>

#define W_OUT 12
#define N_CAPS 288
#define CIN 8
#define DD 16
#define A_DIM 32
#define B_DIM 4
#define CI 32
#define H_IN 14
#define NT 18            // n-rows per lane (288 / 16)
#define XSTRIDE 9        // padded x row stride (floats) — odd => bank spread
#define NROWS 576        // 32 ci * 3 ki * 6 jj

__device__ __forceinline__ float4 shfl_xor4(float4 v, int m) {
    float4 r;
    r.x = __shfl_xor(v.x, m);
    r.y = __shfl_xor(v.y, m);
    r.z = __shfl_xor(v.z, m);
    r.w = __shfl_xor(v.w, m);
    return r;
}

__global__ __launch_bounds__(256, 4) void capsule_kernel(
    const float* __restrict__ x,
    const float* __restrict__ Wt,
    const float* __restrict__ bias,
    float* __restrict__ out)
{
    __shared__ float xs[NROWS * XSTRIDE];   // 20736 B
    __shared__ int   xoff[N_CAPS];          // 1152 B

    const int tid = threadIdx.x;
    int bid = blockIdx.x;
    const int jb = bid % 3; bid /= 3;
    const int i  = bid % W_OUT; bid /= W_OUT;
    const int b  = bid % B_DIM; bid /= B_DIM;
    const int a  = bid;
    const int j0 = jb * 4;

    // xoff[n] = LDS word offset of row n's x data (for sj=0): (ci*18+ki*6+kj)*9
    for (int n = tid; n < N_CAPS; n += 256) {
        int ci = n / 9, r = n % 9;
        xoff[n] = (ci * 18 + (r / 3) * 6 + (r % 3)) * XSTRIDE;
    }

    // stage x window: rows (ci, ki, jj) for jj = 0..5 covering sites j0..j0+3
    for (int row = tid; row < NROWS; row += 256) {
        int ci = row / 18, rr = row % 18;
        int ki = rr / 6, jj = rr % 6;
        const float* src = x + ((((size_t)b * CI + ci) * H_IN + (i + ki)) * H_IN + (j0 + jj)) * CIN;
        float4 v0 = *reinterpret_cast<const float4*>(src);
        float4 v1 = *reinterpret_cast<const float4*>(src + 4);
        float* dst = &xs[row * XSTRIDE];
        dst[0] = v0.x; dst[1] = v0.y; dst[2] = v0.z; dst[3] = v0.w;
        dst[4] = v1.x; dst[5] = v1.y; dst[6] = v1.z; dst[7] = v1.w;
    }
    __syncthreads();
    // ---- no barriers below this point: each wave owns one site ----

    const int lane = tid & 63;
    const int sj   = tid >> 6;          // which of the 4 j-sites (one wave each)
    const int dq   = lane & 3;          // d-quad: lane owns d = 4*dq .. 4*dq+3
    const int nr   = lane >> 2;         // n residue: lane owns n = nr + 16*t

    const float* Wa = Wt + (size_t)a * (N_CAPS * CIN * DD);
    const int sjoff = sj * XSTRIDE;

    // ---- priors in registers: ps[t] = prior[n = nr+16t][4dq..4dq+3]
    // sched_barrier(0) per iteration: R6 post-mortem showed the fully-unrolled
    // loop let the scheduler hoist all 144 float4 W-loads, blowing live range
    // past the 128-VGPR budget -> allocator fell to 64 VGPR + 70 MB scratch
    // spills. The fence caps in-flight loads at 8 (32 VGPRs).
    float4 ps[NT];
    #pragma unroll
    for (int t = 0; t < NT; ++t) {
        const int n = nr + 16 * t;
        const float* wp = Wa + (size_t)n * (CIN * DD) + dq * 4;
        const float* xp = &xs[xoff[n] + sjoff];
        float4 acc = {0.f, 0.f, 0.f, 0.f};
        #pragma unroll
        for (int c = 0; c < CIN; ++c) {
            float4 w4 = *reinterpret_cast<const float4*>(wp + c * DD);
            float xv = xp[c];
            acc.x = fmaf(xv, w4.x, acc.x);
            acc.y = fmaf(xv, w4.y, acc.y);
            acc.z = fmaf(xv, w4.z, acc.z);
            acc.w = fmaf(xv, w4.w, acc.w);
        }
        ps[t] = acc;
        __builtin_amdgcn_sched_barrier(0);
    }

    const float4 bv = *reinterpret_cast<const float4*>(bias + a * DD + dq * 4);

    float lt[NT];     // logits for rows n = nr+16t (replicated across dq lanes)
    float4 out4;

    // ---------- iter 0: logits all zero -> probs = 1/288 ----------
    {
        float4 s = {0.f, 0.f, 0.f, 0.f};
        #pragma unroll
        for (int t = 0; t < NT; ++t) {
            s.x += ps[t].x; s.y += ps[t].y; s.z += ps[t].z; s.w += ps[t].w;
        }
        #pragma unroll
        for (int m = 4; m <= 32; m <<= 1) { float4 o = shfl_xor4(s, m); s.x += o.x; s.y += o.y; s.z += o.z; s.w += o.w; }
        const float inv0 = 1.0f / 288.0f;
        s.x = fmaf(s.x, inv0, bv.x); s.y = fmaf(s.y, inv0, bv.y);
        s.z = fmaf(s.z, inv0, bv.z); s.w = fmaf(s.w, inv0, bv.w);
        float sn = s.x*s.x + s.y*s.y + s.z*s.z + s.w*s.w;
        sn += __shfl_xor(sn, 1); sn += __shfl_xor(sn, 2);
        float factor = sn / (1.0f + sn) * rsqrtf(sn);
        out4.x = factor * s.x; out4.y = factor * s.y; out4.z = factor * s.z; out4.w = factor * s.w;

        #pragma unroll
        for (int t = 0; t < NT; ++t) {
            float p = ps[t].x*out4.x + ps[t].y*out4.y + ps[t].z*out4.z + ps[t].w*out4.w;
            p += __shfl_xor(p, 1);
            p += __shfl_xor(p, 2);
            lt[t] = p;
        }
    }

    // ---------- iters 1, 2 ----------
    #pragma unroll
    for (int it = 1; it < 3; ++it) {
        // softmax over n (288). lt is REPLICATED across the 4 dq lanes, so the
        // denominator reduce must cross nr bits ONLY (masks 4..32) — masks 1,2
        // would count each residue 4x.
        float m = -1e30f;
        #pragma unroll
        for (int t = 0; t < NT; ++t) m = fmaxf(m, lt[t]);
        #pragma unroll
        for (int msk = 4; msk <= 32; msk <<= 1) m = fmaxf(m, __shfl_xor(m, msk));
        float se = 0.f;
        #pragma unroll
        for (int t = 0; t < NT; ++t) se += __expf(lt[t] - m);
        #pragma unroll
        for (int msk = 4; msk <= 32; msk <<= 1) se += __shfl_xor(se, msk);
        const float inv = 1.0f / se;

        float4 s = {0.f, 0.f, 0.f, 0.f};
        #pragma unroll
        for (int t = 0; t < NT; ++t) {
            float e = __expf(lt[t] - m);
            s.x = fmaf(e, ps[t].x, s.x); s.y = fmaf(e, ps[t].y, s.y);
            s.z = fmaf(e, ps[t].z, s.z); s.w = fmaf(e, ps[t].w, s.w);
        }
        #pragma unroll
        for (int msk = 4; msk <= 32; msk <<= 1) { float4 o = shfl_xor4(s, msk); s.x += o.x; s.y += o.y; s.z += o.z; s.w += o.w; }
        s.x = fmaf(s.x, inv, bv.x); s.y = fmaf(s.y, inv, bv.y);
        s.z = fmaf(s.z, inv, bv.z); s.w = fmaf(s.w, inv, bv.w);

        float sn = s.x*s.x + s.y*s.y + s.z*s.z + s.w*s.w;
        sn += __shfl_xor(sn, 1); sn += __shfl_xor(sn, 2);
        float factor = sn / (1.0f + sn) * rsqrtf(sn);
        out4.x = factor * s.x; out4.y = factor * s.y; out4.z = factor * s.z; out4.w = factor * s.w;

        if (it != 2) {
            #pragma unroll
            for (int t = 0; t < NT; ++t) {
                float p = ps[t].x*out4.x + ps[t].y*out4.y + ps[t].z*out4.z + ps[t].w*out4.w;
                p += __shfl_xor(p, 1);
                p += __shfl_xor(p, 2);
                lt[t] += p;
            }
        }
    }

    // ---- store: out[b][a][i][j0+sj][d], 4 lanes (nr==0) x float4 each
    if (nr == 0) {
        size_t o = ((((size_t)b * A_DIM + a) * W_OUT + i) * W_OUT + (j0 + sj)) * DD + dq * 4;
        *reinterpret_cast<float4*>(out + o) = out4;
    }
}

extern "C" void kernel_launch(void* const* d_in, const int* in_sizes, int n_in,
                              void* d_out, int out_size, void* d_ws, size_t ws_size,
                              hipStream_t stream) {
    const float* x    = (const float*)d_in[0];
    const float* Wt   = (const float*)d_in[1];
    const float* bias = (const float*)d_in[2];
    float* out = (float*)d_out;
    (void)in_sizes; (void)n_in; (void)out_size; (void)d_ws; (void)ws_size;

    const int grid = A_DIM * B_DIM * W_OUT * 3;   // 4608 blocks, 4 sites each
    capsule_kernel<<<grid, 256, 0, stream>>>(x, Wt, bias, out);
}

// Round 9
// 142.050 us; speedup vs baseline: 1.9554x; 1.0009x over previous
//
#include <hip/hip_runtime.h>

#define W_OUT 12
#define N_CAPS 288
#define CIN 8
#define DD 16
#define A_DIM 32
#define B_DIM 4
#define CI 32
#define H_IN 14
#define NT 18            // n-rows per lane (288 / 16)
#define XSTRIDE 12       // x row stride (floats): 48B -> 16B-aligned rows, bank-spread
#define NROWS 576        // 32 ci * 3 ki * 6 jj

__device__ __forceinline__ float4 shfl_xor4(float4 v, int m) {
    float4 r;
    r.x = __shfl_xor(v.x, m);
    r.y = __shfl_xor(v.y, m);
    r.z = __shfl_xor(v.z, m);
    r.w = __shfl_xor(v.w, m);
    return r;
}

// acc[d] += xr[c] * wv[c][d]  (8-wide fma accumulate)
__device__ __forceinline__ void fma8(float4& acc, const float* xr, const float4* wv) {
    #pragma unroll
    for (int c = 0; c < CIN; ++c) {
        acc.x = fmaf(xr[c], wv[c].x, acc.x);
        acc.y = fmaf(xr[c], wv[c].y, acc.y);
        acc.z = fmaf(xr[c], wv[c].z, acc.z);
        acc.w = fmaf(xr[c], wv[c].w, acc.w);
    }
}

__global__ __launch_bounds__(256, 3) void capsule_kernel(
    const float* __restrict__ x,
    const float* __restrict__ Wt,
    const float* __restrict__ bias,
    float* __restrict__ out)
{
    __shared__ __align__(16) float xs[NROWS * XSTRIDE];   // 27648 B
    __shared__ int xoff[N_CAPS];                          // 1152 B

    const int tid = threadIdx.x;
    int bid = blockIdx.x;
    const int jb = bid % 3; bid /= 3;
    const int i  = bid % W_OUT; bid /= W_OUT;
    const int b  = bid % B_DIM; bid /= B_DIM;
    const int a  = bid;
    const int j0 = jb * 4;

    // xoff[n] = LDS word offset of row n's x data (for sj=0)
    for (int n = tid; n < N_CAPS; n += 256) {
        int ci = n / 9, r = n % 9;
        xoff[n] = (ci * 18 + (r / 3) * 6 + (r % 3)) * XSTRIDE;
    }

    // stage x window: rows (ci, ki, jj), jj = 0..5 covering sites j0..j0+3
    for (int row = tid; row < NROWS; row += 256) {
        int ci = row / 18, rr = row % 18;
        int ki = rr / 6, jj = rr % 6;
        const float* src = x + ((((size_t)b * CI + ci) * H_IN + (i + ki)) * H_IN + (j0 + jj)) * CIN;
        float4 v0 = *reinterpret_cast<const float4*>(src);
        float4 v1 = *reinterpret_cast<const float4*>(src + 4);
        float* dst = &xs[row * XSTRIDE];
        *reinterpret_cast<float4*>(dst)     = v0;
        *reinterpret_cast<float4*>(dst + 4) = v1;
    }
    __syncthreads();
    // ---- no barriers below this point: each wave owns one site ----

    const int lane = tid & 63;
    const int sj   = tid >> 6;          // which of the 4 j-sites (one wave each)
    const int dq   = lane & 3;          // d-quad: lane owns d = 4*dq .. 4*dq+3
    const int nr   = lane >> 2;         // n residue: lane owns n = nr + 16*t

    const float* Wa = Wt + (size_t)a * (N_CAPS * CIN * DD);
    const int sjoff = sj * XSTRIDE;

    // ---- priors in registers with 1-deep ping-pong W prefetch.
    // R6: no fences -> all 144 loads hoisted -> 64-VGPR fallback + 70 MB spills.
    // R7: fence per t -> serialized on L2 latency (VALUBusy 40%).
    // R8: prefetch t+1 before computing t; sched_barrier(0) after each compute
    //     keeps hoisting bounded to one tile while the waitcnt lands at first
    //     use in the NEXT region -> latency overlaps compute.
    float4 ps[NT];
    float4 wA[CIN], wB[CIN];
    {
        const float* wp0 = Wa + (size_t)nr * (CIN * DD) + dq * 4;
        #pragma unroll
        for (int c = 0; c < CIN; ++c) wA[c] = *reinterpret_cast<const float4*>(wp0 + c * DD);
    }
    #pragma unroll
    for (int tt = 0; tt < NT; tt += 2) {
        {   // prefetch t = tt+1 into wB
            const float* wp = Wa + (size_t)(nr + 16 * (tt + 1)) * (CIN * DD) + dq * 4;
            #pragma unroll
            for (int c = 0; c < CIN; ++c) wB[c] = *reinterpret_cast<const float4*>(wp + c * DD);
        }
        {   // compute t = tt from wA
            const float* xp = &xs[xoff[nr + 16 * tt] + sjoff];
            float xr[CIN];
            *reinterpret_cast<float4*>(&xr[0]) = *reinterpret_cast<const float4*>(xp);
            *reinterpret_cast<float4*>(&xr[4]) = *reinterpret_cast<const float4*>(xp + 4);
            float4 acc = {0.f, 0.f, 0.f, 0.f};
            fma8(acc, xr, wA);
            ps[tt] = acc;
        }
        __builtin_amdgcn_sched_barrier(0);
        if (tt + 2 < NT) {   // prefetch t = tt+2 into wA
            const float* wp = Wa + (size_t)(nr + 16 * (tt + 2)) * (CIN * DD) + dq * 4;
            #pragma unroll
            for (int c = 0; c < CIN; ++c) wA[c] = *reinterpret_cast<const float4*>(wp + c * DD);
        }
        {   // compute t = tt+1 from wB
            const float* xp = &xs[xoff[nr + 16 * (tt + 1)] + sjoff];
            float xr[CIN];
            *reinterpret_cast<float4*>(&xr[0]) = *reinterpret_cast<const float4*>(xp);
            *reinterpret_cast<float4*>(&xr[4]) = *reinterpret_cast<const float4*>(xp + 4);
            float4 acc = {0.f, 0.f, 0.f, 0.f};
            fma8(acc, xr, wB);
            ps[tt + 1] = acc;
        }
        __builtin_amdgcn_sched_barrier(0);
    }

    const float4 bv = *reinterpret_cast<const float4*>(bias + a * DD + dq * 4);

    float lt[NT];     // logits for rows n = nr+16t (replicated across dq lanes)
    float4 out4;

    // ---------- iter 0: logits all zero -> probs = 1/288 ----------
    {
        float4 s = {0.f, 0.f, 0.f, 0.f};
        #pragma unroll
        for (int t = 0; t < NT; ++t) {
            s.x += ps[t].x; s.y += ps[t].y; s.z += ps[t].z; s.w += ps[t].w;
        }
        #pragma unroll
        for (int m = 4; m <= 32; m <<= 1) { float4 o = shfl_xor4(s, m); s.x += o.x; s.y += o.y; s.z += o.z; s.w += o.w; }
        const float inv0 = 1.0f / 288.0f;
        s.x = fmaf(s.x, inv0, bv.x); s.y = fmaf(s.y, inv0, bv.y);
        s.z = fmaf(s.z, inv0, bv.z); s.w = fmaf(s.w, inv0, bv.w);
        float sn = s.x*s.x + s.y*s.y + s.z*s.z + s.w*s.w;
        sn += __shfl_xor(sn, 1); sn += __shfl_xor(sn, 2);
        float factor = sn / (1.0f + sn) * rsqrtf(sn);
        out4.x = factor * s.x; out4.y = factor * s.y; out4.z = factor * s.z; out4.w = factor * s.w;

        #pragma unroll
        for (int t = 0; t < NT; ++t) {
            float p = ps[t].x*out4.x + ps[t].y*out4.y + ps[t].z*out4.z + ps[t].w*out4.w;
            p += __shfl_xor(p, 1);
            p += __shfl_xor(p, 2);
            lt[t] = p;
        }
    }

    // ---------- iters 1, 2 ----------
    #pragma unroll
    for (int it = 1; it < 3; ++it) {
        // lt is REPLICATED across the 4 dq lanes, so softmax reduces must cross
        // nr bits ONLY (masks 4..32) — masks 1,2 would count each residue 4x.
        float m = -1e30f;
        #pragma unroll
        for (int t = 0; t < NT; ++t) m = fmaxf(m, lt[t]);
        #pragma unroll
        for (int msk = 4; msk <= 32; msk <<= 1) m = fmaxf(m, __shfl_xor(m, msk));
        float e[NT];
        float se = 0.f;
        #pragma unroll
        for (int t = 0; t < NT; ++t) { e[t] = __expf(lt[t] - m); se += e[t]; }
        #pragma unroll
        for (int msk = 4; msk <= 32; msk <<= 1) se += __shfl_xor(se, msk);
        const float inv = 1.0f / se;

        float4 s = {0.f, 0.f, 0.f, 0.f};
        #pragma unroll
        for (int t = 0; t < NT; ++t) {
            s.x = fmaf(e[t], ps[t].x, s.x); s.y = fmaf(e[t], ps[t].y, s.y);
            s.z = fmaf(e[t], ps[t].z, s.z); s.w = fmaf(e[t], ps[t].w, s.w);
        }
        #pragma unroll
        for (int msk = 4; msk <= 32; msk <<= 1) { float4 o = shfl_xor4(s, msk); s.x += o.x; s.y += o.y; s.z += o.z; s.w += o.w; }
        s.x = fmaf(s.x, inv, bv.x); s.y = fmaf(s.y, inv, bv.y);
        s.z = fmaf(s.z, inv, bv.z); s.w = fmaf(s.w, inv, bv.w);

        float sn = s.x*s.x + s.y*s.y + s.z*s.z + s.w*s.w;
        sn += __shfl_xor(sn, 1); sn += __shfl_xor(sn, 2);
        float factor = sn / (1.0f + sn) * rsqrtf(sn);
        out4.x = factor * s.x; out4.y = factor * s.y; out4.z = factor * s.z; out4.w = factor * s.w;

        if (it != 2) {
            #pragma unroll
            for (int t = 0; t < NT; ++t) {
                float p = ps[t].x*out4.x + ps[t].y*out4.y + ps[t].z*out4.z + ps[t].w*out4.w;
                p += __shfl_xor(p, 1);
                p += __shfl_xor(p, 2);
                lt[t] += p;
            }
        }
    }

    // ---- store: out[b][a][i][j0+sj][d], 4 lanes (nr==0) x float4 each
    if (nr == 0) {
        size_t o = ((((size_t)b * A_DIM + a) * W_OUT + i) * W_OUT + (j0 + sj)) * DD + dq * 4;
        *reinterpret_cast<float4*>(out + o) = out4;
    }
}

extern "C" void kernel_launch(void* const* d_in, const int* in_sizes, int n_in,
                              void* d_out, int out_size, void* d_ws, size_t ws_size,
                              hipStream_t stream) {
    const float* x    = (const float*)d_in[0];
    const float* Wt   = (const float*)d_in[1];
    const float* bias = (const float*)d_in[2];
    float* out = (float*)d_out;
    (void)in_sizes; (void)n_in; (void)out_size; (void)d_ws; (void)ws_size;

    const int grid = A_DIM * B_DIM * W_OUT * 3;   // 4608 blocks, 4 sites each
    capsule_kernel<<<grid, 256, 0, stream>>>(x, Wt, bias, out);
}